// Round 3
// baseline (1744.675 us; speedup 1.0000x reference)
//
#include <hip/hip_runtime.h>

#define TSTEPS 2048
#define BCOLS  8192
#define TBSZ   (TSTEPS * BCOLS)
#define CHUNKS 32
#define CLEN   64          // TSTEPS / CHUNKS
#define NGRP   128         // BCOLS / 64 column groups (one wave each)
#define PBLK   32          // producer blocks: 32 x 256thr = 128 waves = 128 groups
#define NCONS  512         // consumer blocks; each handles 2 chunks (c, c+16)

// One SEIR step. Shared by all kernels so rounding is identical everywhere.
__device__ __forceinline__ void seir_step(float x, float wb, float wg, float wsg,
                                          float invN,
                                          float& S, float& E, float& I, float& R)
{
    const float s2e = x * wb * I * S * invN;
    const float e2i = x * wsg * E;
    const float i2r = x * wg * I;
    S = S - s2e;
    E = E + s2e - e2i;
    I = I + e2i - i2r;
    R = R + i2r;
}

// ---------------------------------------------------------------------------
// Replay one chunk from a known start state, streaming all outputs.
// Identical to the 378us-verified pass2 inner loop.
// ---------------------------------------------------------------------------
template <int NS>
__device__ __forceinline__ void run_chunk(const float* __restrict__ xp,
                                          float* __restrict__ pS,
                                          float* __restrict__ pE,
                                          float* __restrict__ pI,
                                          float* __restrict__ pR,
                                          float wb, float wg, float wsg, float invN,
                                          float S, float E, float I, float R)
{
    float xbuf[8];
#pragma unroll
    for (int k = 0; k < 8; ++k)
        xbuf[k] = xp[(size_t)k * BCOLS];
#pragma unroll
    for (int t = 0; t < NS; ++t) {
        const float x = xbuf[t & 7];
        if (t + 8 < NS)
            xbuf[t & 7] = xp[(size_t)(t + 8) * BCOLS];
        seir_step(x, wb, wg, wsg, invN, S, E, I, R);
        __builtin_nontemporal_store(S, pS + (size_t)t * BCOLS);
        __builtin_nontemporal_store(E, pE + (size_t)t * BCOLS);
        __builtin_nontemporal_store(I, pI + (size_t)t * BCOLS);
        __builtin_nontemporal_store(R, pR + (size_t)t * BCOLS);
    }
}

// ---------------------------------------------------------------------------
// Consumer side: process one 64-row chunk for this thread's column b.
// Chunk 0 starts from the initial state; chunk c>=1 acquire-polls the
// producer's flag for this 64-col group. On timeout (pathological
// scheduling only) it recomputes the start state itself from t=0 — slow
// but bit-identical, so the kernel can NEVER hang or go wrong.
// ---------------------------------------------------------------------------
__device__ __forceinline__ void consume_chunk(
    int c, int b, int g,
    const float* __restrict__ X,
    const float* __restrict__ S0, const float* __restrict__ I0,
    const float* __restrict__ R0,
    const float* __restrict__ wsp, const unsigned* __restrict__ flags,
    float* __restrict__ out,
    float wb, float wg, float wsg, float invN)
{
    float* oS = out + b;
    float* oE = out + (size_t)TBSZ + b;
    float* oI = out + (size_t)2 * TBSZ + b;
    float* oR = out + (size_t)3 * TBSZ + b;

    if (c == 0) {
        float S = S0[b];
        float E = 0.0f;
        float I = I0[b];
        float R = R0[b];
        __builtin_nontemporal_store(S, oS);
        __builtin_nontemporal_store(0.0f, oE);
        __builtin_nontemporal_store(I, oI);
        __builtin_nontemporal_store(R, oR);
        run_chunk<63>(X + b,
                      oS + BCOLS, oE + BCOLS, oI + BCOLS, oR + BCOLS,
                      wb, wg, wsg, invN, S, E, I, R);
        return;
    }

    const unsigned* fp = &flags[(c - 1) * NGRP + g];
    unsigned f;
    int spins = 0;
    while ((f = __hip_atomic_load(fp, __ATOMIC_ACQUIRE,
                                  __HIP_MEMORY_SCOPE_AGENT)) == 0u) {
        __builtin_amdgcn_s_sleep(16);
        if (++spins > (1 << 18)) break;     // ~0.1 s cap, then self-compute
    }

    float S, E, I, R;
    if (f != 0u) {
        const float* wp = wsp + (size_t)(c - 1) * 4 * BCOLS + b;
        S = wp[0];
        E = wp[(size_t)BCOLS];
        I = wp[(size_t)2 * BCOLS];
        R = wp[(size_t)3 * BCOLS];
    } else {
        // correctness safety net: serial replay from the initial state
        S = S0[b];
        E = 0.0f;
        I = I0[b];
        R = R0[b];
        const float* xq = X + b;
        const int nst = 64 * c - 1;          // consume rows 0 .. 64c-2
#pragma unroll 4
        for (int t = 0; t < nst; ++t)
            seir_step(xq[(size_t)t * BCOLS], wb, wg, wsg, invN, S, E, I, R);
    }

    const size_t t0 = (size_t)c * CLEN - 1;  // first X row consumed
    const size_t r0 = (size_t)c * CLEN;      // first output row written
    run_chunk<64>(X + t0 * BCOLS + b,
                  oS + r0 * BCOLS, oE + r0 * BCOLS,
                  oI + r0 * BCOLS, oR + r0 * BCOLS,
                  wb, wg, wsg, invN, S, E, I, R);
}

// ---------------------------------------------------------------------------
// Fused producer/consumer kernel.
//
// Producer prefetch ring = 32 NAMED SCALARS, manually unrolled. Round-2
// post-mortem: with a float ring[32] array the compiler spilled the ring to
// scratch (VGPR_Count=40 — consumer-path-sized), serializing the sweep at
// ~1300 cyc/step (1104 us). Named scalars cannot be demoted to scratch;
// producer needs ~60 VGPRs, well under the 128 cap from launch_bounds(256,4).
//
// Residency: 544 blocks, 0 LDS, VGPR<=128 -> >=4 blocks/CU -> capacity 1024
// >= 544: all blocks co-resident; spin cannot deadlock. Timeout fallback
// guarantees termination even if that reasoning ever fails.
// ---------------------------------------------------------------------------
__global__ __launch_bounds__(256, 4)
void seir_fused(const float* __restrict__ X,
                const float* __restrict__ w_beta,
                const float* __restrict__ w_gamma,
                const float* __restrict__ w_sigma,
                const float* __restrict__ S0,
                const float* __restrict__ I0,
                const float* __restrict__ R0,
                const float* __restrict__ Nv,
                float* __restrict__ wsp,
                unsigned* __restrict__ flags,
                float* __restrict__ out)
{
    const int wave = threadIdx.x >> 6;
    const int lane = threadIdx.x & 63;

    if (blockIdx.x < PBLK) {
        // ------------------------------ producer ------------------------------
        const int g = blockIdx.x * 4 + wave;   // 64-col group 0..127
        const int b = g * 64 + lane;

        __builtin_amdgcn_s_setprio(1);         // serial chain wins issue arbitration

        const float wb  = w_beta[b];
        const float wg  = w_gamma[b];
        const float wsg = w_sigma[b];
        const float invN = 1.0f / Nv[b];
        float S = S0[b];
        float E = 0.0f;
        float I = I0[b];
        float R = R0[b];

        const float* xp = X + b;

        // 32 named prefetch registers, preloaded with rows 0..31.
#define PRELOAD(i) float r##i = xp[(size_t)(i) * BCOLS];
        PRELOAD(0)  PRELOAD(1)  PRELOAD(2)  PRELOAD(3)
        PRELOAD(4)  PRELOAD(5)  PRELOAD(6)  PRELOAD(7)
        PRELOAD(8)  PRELOAD(9)  PRELOAD(10) PRELOAD(11)
        PRELOAD(12) PRELOAD(13) PRELOAD(14) PRELOAD(15)
        PRELOAD(16) PRELOAD(17) PRELOAD(18) PRELOAD(19)
        PRELOAD(20) PRELOAD(21) PRELOAD(22) PRELOAD(23)
        PRELOAD(24) PRELOAD(25) PRELOAD(26) PRELOAD(27)
        PRELOAD(28) PRELOAD(29) PRELOAD(30) PRELOAD(31)
#undef PRELOAD
        xp += (size_t)32 * BCOLS;

        // consume row, prefetch row 32 ahead
#define PSTEP(i) do {                                                   \
            const float x_ = r##i;                                      \
            r##i = xp[(size_t)(i) * BCOLS];                             \
            seir_step(x_, wb, wg, wsg, invN, S, E, I, R);               \
        } while (0)

        // 61 iterations x 32 steps: consumes rows t = 32j+k, t = 0..1951.
        // Boundary after consuming row t ≡ 62 (mod 64) <=> k==30 && (j odd);
        // idx = (j-1)/2 = 0..29. Iteration j prefetches rows 32(j+1)+k <= 1983.
        for (int j = 0; j < 61; ++j) {
            PSTEP(0);  PSTEP(1);  PSTEP(2);  PSTEP(3);
            PSTEP(4);  PSTEP(5);  PSTEP(6);  PSTEP(7);
            PSTEP(8);  PSTEP(9);  PSTEP(10); PSTEP(11);
            PSTEP(12); PSTEP(13); PSTEP(14); PSTEP(15);
            PSTEP(16); PSTEP(17); PSTEP(18); PSTEP(19);
            PSTEP(20); PSTEP(21); PSTEP(22); PSTEP(23);
            PSTEP(24); PSTEP(25); PSTEP(26); PSTEP(27);
            PSTEP(28); PSTEP(29);
            PSTEP(30);
            if (j & 1) {                       // boundary: consumed row 32j+30
                const int idx = (j - 1) >> 1;  // 0..29
                float* wp = wsp + (size_t)idx * 4 * BCOLS + b;
                wp[0]                 = S;
                wp[(size_t)BCOLS]     = E;
                wp[(size_t)2 * BCOLS] = I;
                wp[(size_t)3 * BCOLS] = R;
                if (lane == 0)
                    __hip_atomic_store(&flags[idx * NGRP + g], 1u,
                                       __ATOMIC_RELEASE,
                                       __HIP_MEMORY_SCOPE_AGENT);
            }
            PSTEP(31);
            xp += (size_t)32 * BCOLS;
        }
#undef PSTEP

        // drain: rows 1952..1982 sit in r0..r30; last step is boundary idx 30
#define DSTEP(i) seir_step(r##i, wb, wg, wsg, invN, S, E, I, R);
        DSTEP(0)  DSTEP(1)  DSTEP(2)  DSTEP(3)
        DSTEP(4)  DSTEP(5)  DSTEP(6)  DSTEP(7)
        DSTEP(8)  DSTEP(9)  DSTEP(10) DSTEP(11)
        DSTEP(12) DSTEP(13) DSTEP(14) DSTEP(15)
        DSTEP(16) DSTEP(17) DSTEP(18) DSTEP(19)
        DSTEP(20) DSTEP(21) DSTEP(22) DSTEP(23)
        DSTEP(24) DSTEP(25) DSTEP(26) DSTEP(27)
        DSTEP(28) DSTEP(29) DSTEP(30)
#undef DSTEP
        {
            float* wp = wsp + (size_t)30 * 4 * BCOLS + b;
            wp[0]                 = S;
            wp[(size_t)BCOLS]     = E;
            wp[(size_t)2 * BCOLS] = I;
            wp[(size_t)3 * BCOLS] = R;
            if (lane == 0)
                __hip_atomic_store(&flags[30 * NGRP + g], 1u,
                                   __ATOMIC_RELEASE, __HIP_MEMORY_SCOPE_AGENT);
        }
    } else {
        // ------------------------------ consumer ------------------------------
        const int idx = (int)blockIdx.x - PBLK;       // 0..511
        const int G   = idx & 31;                     // 256-col group
        const int cp  = idx >> 5;                     // 0..15
        const int g   = G * 4 + wave;                 // 64-col group 0..127
        const int b   = g * 64 + lane;

        const float wb  = w_beta[b];
        const float wg  = w_gamma[b];
        const float wsg = w_sigma[b];
        const float invN = 1.0f / Nv[b];

        consume_chunk(cp, b, g, X, S0, I0, R0, wsp, flags, out,
                      wb, wg, wsg, invN);
        consume_chunk(cp + 16, b, g, X, S0, I0, R0, wsp, flags, out,
                      wb, wg, wsg, invN);
    }
}

// ---------------------------------------------------------------------------
// Fallback: single-kernel version (used only if ws_size is too small).
// ---------------------------------------------------------------------------
__global__ __launch_bounds__(64)
void seir_mono(const float* __restrict__ X,
               const float* __restrict__ w_beta,
               const float* __restrict__ w_gamma,
               const float* __restrict__ w_sigma,
               const float* __restrict__ S0,
               const float* __restrict__ I0,
               const float* __restrict__ R0,
               const float* __restrict__ Nv,
               float* __restrict__ out)
{
    const int b = blockIdx.x * 64 + threadIdx.x;
    const float wb  = w_beta[b];
    const float wg  = w_gamma[b];
    const float wsg = w_sigma[b];
    float S = S0[b];
    float E = 0.0f;
    float I = I0[b];
    float R = R0[b];
    const float invN = 1.0f / Nv[b];

    float* oS = out + b;
    float* oE = out + (size_t)TBSZ + b;
    float* oI = out + (size_t)2 * TBSZ + b;
    float* oR = out + (size_t)3 * TBSZ + b;

    __builtin_nontemporal_store(S, oS);
    __builtin_nontemporal_store(0.0f, oE);
    __builtin_nontemporal_store(I, oI);
    __builtin_nontemporal_store(R, oR);

    const float* xp = X + b;
    float xc[8];
#pragma unroll
    for (int k = 0; k < 8; ++k)
        xc[k] = __builtin_nontemporal_load(xp + (size_t)k * BCOLS);
    xp += (size_t)8 * BCOLS;

    for (int i = 0; i < 255; ++i) {
        float xn[8];
#pragma unroll
        for (int k = 0; k < 8; ++k)
            xn[k] = __builtin_nontemporal_load(xp + (size_t)k * BCOLS);
        xp += (size_t)8 * BCOLS;

        float* pS = oS + (size_t)(8 * i + 1) * BCOLS;
        float* pE = oE + (size_t)(8 * i + 1) * BCOLS;
        float* pI = oI + (size_t)(8 * i + 1) * BCOLS;
        float* pR = oR + (size_t)(8 * i + 1) * BCOLS;

#pragma unroll
        for (int k = 0; k < 8; ++k) {
            seir_step(xc[k], wb, wg, wsg, invN, S, E, I, R);
            __builtin_nontemporal_store(S, pS + (size_t)k * BCOLS);
            __builtin_nontemporal_store(E, pE + (size_t)k * BCOLS);
            __builtin_nontemporal_store(I, pI + (size_t)k * BCOLS);
            __builtin_nontemporal_store(R, pR + (size_t)k * BCOLS);
        }
#pragma unroll
        for (int k = 0; k < 8; ++k) xc[k] = xn[k];
    }
    {
        float* pS = oS + (size_t)2041 * BCOLS;
        float* pE = oE + (size_t)2041 * BCOLS;
        float* pI = oI + (size_t)2041 * BCOLS;
        float* pR = oR + (size_t)2041 * BCOLS;
#pragma unroll
        for (int k = 0; k < 7; ++k) {
            seir_step(xc[k], wb, wg, wsg, invN, S, E, I, R);
            __builtin_nontemporal_store(S, pS + (size_t)k * BCOLS);
            __builtin_nontemporal_store(E, pE + (size_t)k * BCOLS);
            __builtin_nontemporal_store(I, pI + (size_t)k * BCOLS);
            __builtin_nontemporal_store(R, pR + (size_t)k * BCOLS);
        }
    }
}

extern "C" void kernel_launch(void* const* d_in, const int* in_sizes, int n_in,
                              void* d_out, int out_size, void* d_ws, size_t ws_size,
                              hipStream_t stream)
{
    (void)in_sizes; (void)n_in; (void)out_size;

    const float* X      = (const float*)d_in[0];
    const float* w_beta = (const float*)d_in[1];
    const float* w_gamma= (const float*)d_in[2];
    const float* w_sigma= (const float*)d_in[3];
    const float* S0     = (const float*)d_in[4];
    const float* I0     = (const float*)d_in[5];
    const float* R0     = (const float*)d_in[6];
    const float* Nv     = (const float*)d_in[7];
    float* out          = (float*)d_out;

    const size_t state_bytes = (size_t)(CHUNKS - 1) * 4 * BCOLS * sizeof(float); // ~3.9 MB
    const size_t flag_bytes  = (size_t)(CHUNKS - 1) * NGRP * sizeof(unsigned);   // ~15.9 KB
    if (ws_size < state_bytes + flag_bytes) {
        seir_mono<<<dim3(BCOLS / 64), dim3(64), 0, stream>>>(
            X, w_beta, w_gamma, w_sigma, S0, I0, R0, Nv, out);
        return;
    }

    float* wsp      = (float*)d_ws;
    unsigned* flags = (unsigned*)((char*)d_ws + state_bytes);

    // Flags live in poisoned workspace: zero them every launch (graph-legal).
    hipMemsetAsync(flags, 0, flag_bytes, stream);

    seir_fused<<<dim3(PBLK + NCONS), dim3(256), 0, stream>>>(
        X, w_beta, w_gamma, w_sigma, S0, I0, R0, Nv, wsp, flags, out);
}

// Round 4
// 405.160 us; speedup vs baseline: 4.3061x; 4.3061x over previous
//
#include <hip/hip_runtime.h>

#define TSTEPS 2048
#define BCOLS  8192
#define TBSZ   (TSTEPS * BCOLS)
#define CHUNKS 32
#define CLEN   64          // TSTEPS / CHUNKS

typedef float f4 __attribute__((ext_vector_type(4)));

// One SEIR step. Shared by all kernels so rounding is identical everywhere.
__device__ __forceinline__ void seir_step(float x, float wb, float wg, float wsg,
                                          float invN,
                                          float& S, float& E, float& I, float& R)
{
    const float s2e = x * wb * I * S * invN;
    const float e2i = x * wsg * E;
    const float i2r = x * wg * I;
    S = S - s2e;
    E = E + s2e - e2i;
    I = I + e2i - i2r;
    R = R + i2r;
}

// 4 independent columns per thread (ILP-4). Component-wise identical to
// seir_step, so rounding matches the scalar path bit-for-bit.
__device__ __forceinline__ void seir_step4(f4 x, f4 wb, f4 wg, f4 wsg, f4 iN,
                                           f4& S, f4& E, f4& I, f4& R)
{
#pragma unroll
    for (int c = 0; c < 4; ++c) {
        float s = S[c], e = E[c], i = I[c], r = R[c];
        seir_step(x[c], wb[c], wg[c], wsg[c], iN[c], s, e, i, r);
        S[c] = s; E[c] = e; I[c] = i; R[c] = r;
    }
}

// ---------------------------------------------------------------------------
// Pass 1: sequential recurrence, compute-only, saves states at chunk
// boundaries (after consuming X row t with t ≡ 62 mod 64 → start state for
// chunk c = idx+1). Standalone kernel, __launch_bounds__(64,1): min-waves=1
// removes the backend's occupancy/pressure target, so the scheduler has no
// incentive to sink the prefetch loads (the round-2/3 fused-kernel failure
// mode: ring collapsed to depth 0, VGPR_Count 36-40, ~1900 cyc/step).
// 32-deep ring of NAMED scalars: 8192 threads x 32 x 4 B = 1 MB in flight.
// ---------------------------------------------------------------------------
__global__ __launch_bounds__(64, 1)
void seir_pass1(const float* __restrict__ X,
                const float* __restrict__ w_beta,
                const float* __restrict__ w_gamma,
                const float* __restrict__ w_sigma,
                const float* __restrict__ S0,
                const float* __restrict__ I0,
                const float* __restrict__ R0,
                const float* __restrict__ Nv,
                float* __restrict__ wsp)
{
    const int b = blockIdx.x * 64 + threadIdx.x;

    const float wb  = w_beta[b];
    const float wg  = w_gamma[b];
    const float wsg = w_sigma[b];
    const float invN = 1.0f / Nv[b];
    float S = S0[b];
    float E = 0.0f;
    float I = I0[b];
    float R = R0[b];

    const float* xp = X + b;

    // 32 named prefetch registers, preloaded with rows 0..31.
#define PRELOAD(i) float r##i = xp[(size_t)(i) * BCOLS];
    PRELOAD(0)  PRELOAD(1)  PRELOAD(2)  PRELOAD(3)
    PRELOAD(4)  PRELOAD(5)  PRELOAD(6)  PRELOAD(7)
    PRELOAD(8)  PRELOAD(9)  PRELOAD(10) PRELOAD(11)
    PRELOAD(12) PRELOAD(13) PRELOAD(14) PRELOAD(15)
    PRELOAD(16) PRELOAD(17) PRELOAD(18) PRELOAD(19)
    PRELOAD(20) PRELOAD(21) PRELOAD(22) PRELOAD(23)
    PRELOAD(24) PRELOAD(25) PRELOAD(26) PRELOAD(27)
    PRELOAD(28) PRELOAD(29) PRELOAD(30) PRELOAD(31)
#undef PRELOAD
    xp += (size_t)32 * BCOLS;

    // consume row, prefetch the row 32 ahead
#define PSTEP(i) do {                                                   \
        const float x_ = r##i;                                          \
        r##i = xp[(size_t)(i) * BCOLS];                                 \
        seir_step(x_, wb, wg, wsg, invN, S, E, I, R);                   \
    } while (0)

    // 61 iterations x 32 steps: consumes rows t = 32j+k, t = 0..1951.
    // Boundary after row t ≡ 62 (mod 64) <=> k==30 && (j odd); idx=(j-1)/2.
    // Iteration j prefetches rows 32(j+1)+k <= 1983 (< 2048, in bounds).
    for (int j = 0; j < 61; ++j) {
        PSTEP(0);  PSTEP(1);  PSTEP(2);  PSTEP(3);
        PSTEP(4);  PSTEP(5);  PSTEP(6);  PSTEP(7);
        PSTEP(8);  PSTEP(9);  PSTEP(10); PSTEP(11);
        PSTEP(12); PSTEP(13); PSTEP(14); PSTEP(15);
        PSTEP(16); PSTEP(17); PSTEP(18); PSTEP(19);
        PSTEP(20); PSTEP(21); PSTEP(22); PSTEP(23);
        PSTEP(24); PSTEP(25); PSTEP(26); PSTEP(27);
        PSTEP(28); PSTEP(29);
        PSTEP(30);
        if (j & 1) {                       // boundary: consumed row 32j+30
            const int idx = (j - 1) >> 1;  // 0..29
            float* wp = wsp + (size_t)idx * 4 * BCOLS + b;
            wp[0]                 = S;
            wp[(size_t)BCOLS]     = E;
            wp[(size_t)2 * BCOLS] = I;
            wp[(size_t)3 * BCOLS] = R;
        }
        PSTEP(31);
        xp += (size_t)32 * BCOLS;
    }
#undef PSTEP

    // drain: rows 1952..1982 sit in r0..r30; last step is boundary idx 30
#define DSTEP(i) seir_step(r##i, wb, wg, wsg, invN, S, E, I, R);
    DSTEP(0)  DSTEP(1)  DSTEP(2)  DSTEP(3)
    DSTEP(4)  DSTEP(5)  DSTEP(6)  DSTEP(7)
    DSTEP(8)  DSTEP(9)  DSTEP(10) DSTEP(11)
    DSTEP(12) DSTEP(13) DSTEP(14) DSTEP(15)
    DSTEP(16) DSTEP(17) DSTEP(18) DSTEP(19)
    DSTEP(20) DSTEP(21) DSTEP(22) DSTEP(23)
    DSTEP(24) DSTEP(25) DSTEP(26) DSTEP(27)
    DSTEP(28) DSTEP(29) DSTEP(30)
#undef DSTEP
    {
        float* wp = wsp + (size_t)30 * 4 * BCOLS + b;
        wp[0]                 = S;
        wp[(size_t)BCOLS]     = E;
        wp[(size_t)2 * BCOLS] = I;
        wp[(size_t)3 * BCOLS] = R;
    }
}

// ---------------------------------------------------------------------------
// Pass 2: replay one 64-step chunk, 4 columns per thread.
// Per step: one dwordx4 X load, 4 independent SEIR chains (ILP hides the
// ~22-cyc dep chain), four nontemporal dwordx4 stores (vs 16 dword stores
// in the 378us version — 4x fewer store instructions at the same bytes).
// ---------------------------------------------------------------------------
template <int NS>
__device__ __forceinline__ void run_chunk4(const float* __restrict__ xp,
                                           float* __restrict__ pS,
                                           float* __restrict__ pE,
                                           float* __restrict__ pI,
                                           float* __restrict__ pR,
                                           f4 wb, f4 wg, f4 wsg, f4 iN,
                                           f4 S, f4 E, f4 I, f4 R)
{
    f4 xbuf[8];
#pragma unroll
    for (int k = 0; k < 8; ++k)
        xbuf[k] = *(const f4*)(xp + (size_t)k * BCOLS);
#pragma unroll
    for (int t = 0; t < NS; ++t) {
        const f4 x = xbuf[t & 7];
        if (t + 8 < NS)
            xbuf[t & 7] = *(const f4*)(xp + (size_t)(t + 8) * BCOLS);
        seir_step4(x, wb, wg, wsg, iN, S, E, I, R);
        __builtin_nontemporal_store(S, (f4*)(pS + (size_t)t * BCOLS));
        __builtin_nontemporal_store(E, (f4*)(pE + (size_t)t * BCOLS));
        __builtin_nontemporal_store(I, (f4*)(pI + (size_t)t * BCOLS));
        __builtin_nontemporal_store(R, (f4*)(pR + (size_t)t * BCOLS));
    }
}

__global__ __launch_bounds__(64, 1)
void seir_pass2(const float* __restrict__ X,
                const float* __restrict__ w_beta,
                const float* __restrict__ w_gamma,
                const float* __restrict__ w_sigma,
                const float* __restrict__ S0,
                const float* __restrict__ I0,
                const float* __restrict__ R0,
                const float* __restrict__ Nv,
                const float* __restrict__ wsp,
                float* __restrict__ out)
{
    const int tid = blockIdx.x * 64 + threadIdx.x;   // 0..2047
    const int cb  = tid * 4;                         // column base (16B aligned)
    const int c   = blockIdx.y;                      // chunk 0..31

    const f4 wb  = *(const f4*)(w_beta  + cb);
    const f4 wg  = *(const f4*)(w_gamma + cb);
    const f4 wsg = *(const f4*)(w_sigma + cb);
    const f4 n4  = *(const f4*)(Nv + cb);
    f4 iN;
#pragma unroll
    for (int k = 0; k < 4; ++k) iN[k] = 1.0f / n4[k];   // same op as scalar path

    float* oS = out + cb;
    float* oE = out + (size_t)TBSZ + cb;
    float* oI = out + (size_t)2 * TBSZ + cb;
    float* oR = out + (size_t)3 * TBSZ + cb;

    if (c == 0) {
        const f4 S = *(const f4*)(S0 + cb);
        const f4 E = {0.0f, 0.0f, 0.0f, 0.0f};
        const f4 I = *(const f4*)(I0 + cb);
        const f4 R = *(const f4*)(R0 + cb);
        __builtin_nontemporal_store(S, (f4*)oS);
        __builtin_nontemporal_store(E, (f4*)oE);
        __builtin_nontemporal_store(I, (f4*)oI);
        __builtin_nontemporal_store(R, (f4*)oR);
        run_chunk4<63>(X + cb,
                       oS + BCOLS, oE + BCOLS, oI + BCOLS, oR + BCOLS,
                       wb, wg, wsg, iN, S, E, I, R);
    } else {
        const float* wp = wsp + (size_t)(c - 1) * 4 * BCOLS + cb;
        const f4 S = *(const f4*)(wp);
        const f4 E = *(const f4*)(wp + (size_t)BCOLS);
        const f4 I = *(const f4*)(wp + (size_t)2 * BCOLS);
        const f4 R = *(const f4*)(wp + (size_t)3 * BCOLS);
        const size_t t0 = (size_t)c * CLEN - 1;   // first X row consumed
        const size_t r0 = (size_t)c * CLEN;       // first output row written
        run_chunk4<64>(X + t0 * BCOLS + cb,
                       oS + r0 * BCOLS, oE + r0 * BCOLS,
                       oI + r0 * BCOLS, oR + r0 * BCOLS,
                       wb, wg, wsg, iN, S, E, I, R);
    }
}

// ---------------------------------------------------------------------------
// Fallback: single-kernel version (used only if ws_size is too small).
// ---------------------------------------------------------------------------
__global__ __launch_bounds__(64)
void seir_mono(const float* __restrict__ X,
               const float* __restrict__ w_beta,
               const float* __restrict__ w_gamma,
               const float* __restrict__ w_sigma,
               const float* __restrict__ S0,
               const float* __restrict__ I0,
               const float* __restrict__ R0,
               const float* __restrict__ Nv,
               float* __restrict__ out)
{
    const int b = blockIdx.x * 64 + threadIdx.x;
    const float wb  = w_beta[b];
    const float wg  = w_gamma[b];
    const float wsg = w_sigma[b];
    float S = S0[b];
    float E = 0.0f;
    float I = I0[b];
    float R = R0[b];
    const float invN = 1.0f / Nv[b];

    float* oS = out + b;
    float* oE = out + (size_t)TBSZ + b;
    float* oI = out + (size_t)2 * TBSZ + b;
    float* oR = out + (size_t)3 * TBSZ + b;

    __builtin_nontemporal_store(S, oS);
    __builtin_nontemporal_store(0.0f, oE);
    __builtin_nontemporal_store(I, oI);
    __builtin_nontemporal_store(R, oR);

    const float* xp = X + b;
    float xc[8];
#pragma unroll
    for (int k = 0; k < 8; ++k)
        xc[k] = __builtin_nontemporal_load(xp + (size_t)k * BCOLS);
    xp += (size_t)8 * BCOLS;

    for (int i = 0; i < 255; ++i) {
        float xn[8];
#pragma unroll
        for (int k = 0; k < 8; ++k)
            xn[k] = __builtin_nontemporal_load(xp + (size_t)k * BCOLS);
        xp += (size_t)8 * BCOLS;

        float* pS = oS + (size_t)(8 * i + 1) * BCOLS;
        float* pE = oE + (size_t)(8 * i + 1) * BCOLS;
        float* pI = oI + (size_t)(8 * i + 1) * BCOLS;
        float* pR = oR + (size_t)(8 * i + 1) * BCOLS;

#pragma unroll
        for (int k = 0; k < 8; ++k) {
            seir_step(xc[k], wb, wg, wsg, invN, S, E, I, R);
            __builtin_nontemporal_store(S, pS + (size_t)k * BCOLS);
            __builtin_nontemporal_store(E, pE + (size_t)k * BCOLS);
            __builtin_nontemporal_store(I, pI + (size_t)k * BCOLS);
            __builtin_nontemporal_store(R, pR + (size_t)k * BCOLS);
        }
#pragma unroll
        for (int k = 0; k < 8; ++k) xc[k] = xn[k];
    }
    {
        float* pS = oS + (size_t)2041 * BCOLS;
        float* pE = oE + (size_t)2041 * BCOLS;
        float* pI = oI + (size_t)2041 * BCOLS;
        float* pR = oR + (size_t)2041 * BCOLS;
#pragma unroll
        for (int k = 0; k < 7; ++k) {
            seir_step(xc[k], wb, wg, wsg, invN, S, E, I, R);
            __builtin_nontemporal_store(S, pS + (size_t)k * BCOLS);
            __builtin_nontemporal_store(E, pE + (size_t)k * BCOLS);
            __builtin_nontemporal_store(I, pI + (size_t)k * BCOLS);
            __builtin_nontemporal_store(R, pR + (size_t)k * BCOLS);
        }
    }
}

extern "C" void kernel_launch(void* const* d_in, const int* in_sizes, int n_in,
                              void* d_out, int out_size, void* d_ws, size_t ws_size,
                              hipStream_t stream)
{
    (void)in_sizes; (void)n_in; (void)out_size;

    const float* X      = (const float*)d_in[0];
    const float* w_beta = (const float*)d_in[1];
    const float* w_gamma= (const float*)d_in[2];
    const float* w_sigma= (const float*)d_in[3];
    const float* S0     = (const float*)d_in[4];
    const float* I0     = (const float*)d_in[5];
    const float* R0     = (const float*)d_in[6];
    const float* Nv     = (const float*)d_in[7];
    float* out          = (float*)d_out;

    const size_t need = (size_t)(CHUNKS - 1) * 4 * BCOLS * sizeof(float); // ~3.9 MB
    if (ws_size < need) {
        seir_mono<<<dim3(BCOLS / 64), dim3(64), 0, stream>>>(
            X, w_beta, w_gamma, w_sigma, S0, I0, R0, Nv, out);
        return;
    }

    float* wsp = (float*)d_ws;
    seir_pass1<<<dim3(BCOLS / 64), dim3(64), 0, stream>>>(
        X, w_beta, w_gamma, w_sigma, S0, I0, R0, Nv, wsp);
    seir_pass2<<<dim3(BCOLS / 256, CHUNKS), dim3(64), 0, stream>>>(
        X, w_beta, w_gamma, w_sigma, S0, I0, R0, Nv, wsp, out);
}